// Round 6
// baseline (5961.175 us; speedup 1.0000x reference)
//
#include <hip/hip_runtime.h>
#include <cstdint>
#include <cstddef>

// ---------------- types ----------------
typedef float    f32x4  __attribute__((ext_vector_type(4)));
typedef short    s16x8  __attribute__((ext_vector_type(8)));
typedef _Float16 f16x8  __attribute__((ext_vector_type(8)));
typedef uint16_t u16x4  __attribute__((ext_vector_type(4)));

// ---------------- problem dims ----------------
#define D_B 256
#define D_S 16
#define D_W 32
#define D_T 512      // S*W
#define D_V 30000
#define D_E 256
#define D_H 512
#define D_G 2048     // 4*H
#define D_C 5
#define NWG 64       // sequential-phase workgroups (j-split of gate rows)

// ---------------- workspace layout (bytes) ----------------
constexpr size_t OFF_EG    = 0;                                   // f16 [V][2048]  (perm cols)
constexpr size_t OFF_EMB   = OFF_EG   + (size_t)D_V * D_G * 2;    // f16 [V][256]
constexpr size_t OFF_WIH   = OFF_EMB  + (size_t)D_V * D_E * 2;    // f16 perm [2048][256]
constexpr size_t OFF_WHH   = OFF_WIH  + (size_t)D_G * D_E * 2;    // f16 perm [2048][512]
constexpr size_t OFF_BIAS  = OFF_WHH  + (size_t)D_G * D_H * 2;    // f32 perm [2048]
constexpr size_t OFF_HBUF  = OFF_BIAS + (size_t)D_G * 4;          // f16 [2][256][512]
constexpr size_t OFF_FLAGS = OFF_HBUF + (size_t)2 * D_B * D_H * 2; // i32 [4 wv][64 wg]
constexpr size_t OFF_REPS  = OFF_FLAGS + (size_t)256 * 4;         // f32 [16][256][512]
constexpr size_t OFF_A     = OFF_REPS + (size_t)D_S * D_B * D_H * 4;  // f32 [16][256][5]
constexpr size_t OFF_A0    = OFF_A    + (size_t)D_S * D_B * D_C * 4;  // f32 [3][256][5]
constexpr size_t OFF_ABT   = OFF_A0   + (size_t)3 * D_B * D_C * 4;    // i32 [512][256]

// ---------------- helpers ----------------
__device__ __forceinline__ uint16_t f2h(float f) {
    _Float16 h = (_Float16)f;
    return __builtin_bit_cast(uint16_t, h);
}
__device__ __forceinline__ float sigm(float x)  { return 1.0f / (1.0f + __expf(-x)); }
__device__ __forceinline__ float tanh_fast(float x) { return 1.0f - 2.0f / (__expf(2.0f * x) + 1.0f); }

// counted VMEM wait + scheduler fence (rule 18: consumers must not hoist)
#define VWAIT(N) do { asm volatile("s_waitcnt vmcnt(" #N ")" ::: "memory"); \
                      __builtin_amdgcn_sched_barrier(0); } while (0)
#define SBAR()   __builtin_amdgcn_sched_barrier(0)

// ---- LLC-coherent (cross-XCD) access: sc0 sc1 bypasses L1+L2 per access.
__device__ __forceinline__ int load_flag_llc(const int* p) {
    int v;
    asm volatile("global_load_dword %0, %1, off sc0 sc1\n\ts_waitcnt vmcnt(0)"
                 : "=v"(v) : "v"(p) : "memory");
    return v;
}
__device__ __forceinline__ void store_flag_llc(int* p, int v) {
    asm volatile("global_store_dword %0, %1, off sc0 sc1" :: "v"(p), "v"(v) : "memory");
}
__device__ __forceinline__ void store_dword_llc(int* p, int v) {
    asm volatile("global_store_dword %0, %1, off sc0 sc1" :: "v"(p), "v"(v) : "memory");
}
__device__ __forceinline__ void store16_llc(void* p, f32x4 v) {
    asm volatile("global_store_dwordx4 %0, %1, off sc0 sc1" :: "v"(p), "v"(v) : "memory");
}
__device__ __forceinline__ void store_h_nowait(uint16_t* p, f16x8 v) {
    asm volatile("global_store_dwordx4 %0, %1, off sc0 sc1" :: "v"(p), "v"(v) : "memory");
}
// cached (L1/L2) token prefetch, no wait — drained by the next poll's vmcnt(0)
__device__ __forceinline__ void issue_tok(const int* p, int& v) {
    asm volatile("global_load_dword %0, %1, off" : "=&v"(v) : "v"(p) : "memory");
}
// cached EG prefetch (64B slice), no wait
__device__ __forceinline__ void issue_eg(const uint16_t* p, f16x8& a, f16x8& b2,
                                         f16x8& c, f16x8& d) {
    asm volatile(
        "global_load_dwordx4 %0, %4, off\n\t"
        "global_load_dwordx4 %1, %4, off offset:16\n\t"
        "global_load_dwordx4 %2, %4, off offset:32\n\t"
        "global_load_dwordx4 %3, %4, off offset:48"
        : "=&v"(a), "=&v"(b2), "=&v"(c), "=&v"(d)
        : "v"(p) : "memory");
}
// 8 batched LLC loads (one K-half of one m-tile), NO wait (pipelined).
__device__ __forceinline__ void issue_h8(const uint16_t* base, f16x8* A) {
    asm volatile(
        "global_load_dwordx4 %0, %8, off sc0 sc1\n\t"
        "global_load_dwordx4 %1, %8, off offset:64 sc0 sc1\n\t"
        "global_load_dwordx4 %2, %8, off offset:128 sc0 sc1\n\t"
        "global_load_dwordx4 %3, %8, off offset:192 sc0 sc1\n\t"
        "global_load_dwordx4 %4, %8, off offset:256 sc0 sc1\n\t"
        "global_load_dwordx4 %5, %8, off offset:320 sc0 sc1\n\t"
        "global_load_dwordx4 %6, %8, off offset:384 sc0 sc1\n\t"
        "global_load_dwordx4 %7, %8, off offset:448 sc0 sc1"
        : "=&v"(A[0]), "=&v"(A[1]), "=&v"(A[2]), "=&v"(A[3]),
          "=&v"(A[4]), "=&v"(A[5]), "=&v"(A[6]), "=&v"(A[7])
        : "v"(base) : "memory");
}

// ======================================================================
// prep (unchanged from round 4)
// ======================================================================
__global__ __launch_bounds__(256) void prep_kernel(
    const int* __restrict__ abstracts,
    const float* __restrict__ emb, const float* __restrict__ Wih,
    const float* __restrict__ Whh, const float* __restrict__ bih,
    const float* __restrict__ bhh,
    uint16_t* __restrict__ embB, uint16_t* __restrict__ WihP,
    uint16_t* __restrict__ WhhP, float* __restrict__ biasP,
    uint16_t* __restrict__ hbuf0, int* __restrict__ flags,
    int* __restrict__ abT)
{
    const long NA = (long)D_V * D_E / 4;
    const long NB = (long)D_G * D_E / 4;
    const long NC = (long)D_G * D_H / 4;
    const long ND = D_G;
    const long NE = (long)D_B * D_H / 8;
    const long NF = 256;
    const long NG = (long)D_T * D_B;
    const long TOT = NA + NB + NC + ND + NE + NF + NG;
    long stride = (long)gridDim.x * blockDim.x;
    for (long i = (long)blockIdx.x * blockDim.x + threadIdx.x; i < TOT; i += stride) {
        if (i < NA) {
            f32x4 v = ((const f32x4*)emb)[i];
            u16x4 o = { f2h(v[0]), f2h(v[1]), f2h(v[2]), f2h(v[3]) };
            ((u16x4*)embB)[i] = o;
        } else if (i < NA + NB) {
            long j = i - NA; long flat = j * 4;
            int r = (int)(flat >> 8), e0 = (int)(flat & 255);
            int p = ((r & 511) << 2) | (r >> 9);
            f32x4 v = ((const f32x4*)Wih)[j];
            u16x4 o = { f2h(v[0]), f2h(v[1]), f2h(v[2]), f2h(v[3]) };
            *(u16x4*)(WihP + (size_t)p * D_E + e0) = o;
        } else if (i < NA + NB + NC) {
            long j = i - NA - NB; long flat = j * 4;
            int r = (int)(flat >> 9), k0 = (int)(flat & 511);
            int p = ((r & 511) << 2) | (r >> 9);
            f32x4 v = ((const f32x4*)Whh)[j];
            u16x4 o = { f2h(v[0]), f2h(v[1]), f2h(v[2]), f2h(v[3]) };
            *(u16x4*)(WhhP + (size_t)p * D_H + k0) = o;
        } else if (i < NA + NB + NC + ND) {
            int p = (int)(i - NA - NB - NC);
            int r = ((p & 3) << 9) | (p >> 2);
            biasP[p] = bih[r] + bhh[r];
        } else if (i < NA + NB + NC + ND + NE) {
            long j = i - NA - NB - NC - ND;
            f32x4 z = (f32x4)0.0f;
            store16_llc(hbuf0 + j * 8, z);
        } else if (i < NA + NB + NC + ND + NE + NF) {
            long j = i - NA - NB - NC - ND - NE;
            store_dword_llc(flags + j, 0);
        } else {
            long j = i - NA - NB - NC - ND - NE - NF;
            int t = (int)(j >> 8), b = (int)(j & 255);
            abT[(size_t)t * D_B + b] = abstracts[(size_t)b * D_T + t];
        }
    }
    asm volatile("s_waitcnt vmcnt(0)" ::: "memory");  // drain LLC stores
}

// ======================================================================
// egemm (unchanged from round 4)
// ======================================================================
__global__ __launch_bounds__(256) void egemm_kernel(
    const uint16_t* __restrict__ embB, const uint16_t* __restrict__ WihP,
    uint16_t* __restrict__ EG)
{
    int nt = blockIdx.x;
    int mt = blockIdx.y;
    int tid = threadIdx.x, lane = tid & 63, wv = tid >> 6;
    int v0 = mt * 128, n0 = nt * 128;
    __shared__ uint16_t As[128][40];
    __shared__ uint16_t Bs[128][40];
    f32x4 acc[4][4];
#pragma unroll
    for (int a = 0; a < 4; ++a)
#pragma unroll
        for (int bb = 0; bb < 4; ++bb) acc[a][bb] = (f32x4)0.0f;
    int wm = (wv >> 1) * 64, wn = (wv & 1) * 64;
    int row = tid >> 1, half = tid & 1;
    for (int kb = 0; kb < 8; ++kb) {
        int k0 = kb * 32;
        int vrow = v0 + row; if (vrow > D_V - 1) vrow = D_V - 1;
        const s16x8* pa = (const s16x8*)(embB + (size_t)vrow * D_E + k0 + half * 16);
        *(s16x8*)&As[row][half * 16]     = pa[0];
        *(s16x8*)&As[row][half * 16 + 8] = pa[1];
        const s16x8* pb = (const s16x8*)(WihP + (size_t)(n0 + row) * D_E + k0 + half * 16);
        *(s16x8*)&Bs[row][half * 16]     = pb[0];
        *(s16x8*)&Bs[row][half * 16 + 8] = pb[1];
        __syncthreads();
        int krow = (lane >> 4) * 8;
        f16x8 af[4], bfr[4];
#pragma unroll
        for (int i = 0; i < 4; ++i) af[i]  = *(const f16x8*)&As[wm + i * 16 + (lane & 15)][krow];
#pragma unroll
        for (int i = 0; i < 4; ++i) bfr[i] = *(const f16x8*)&Bs[wn + i * 16 + (lane & 15)][krow];
#pragma unroll
        for (int mi = 0; mi < 4; ++mi)
#pragma unroll
            for (int ni = 0; ni < 4; ++ni)
                acc[mi][ni] = __builtin_amdgcn_mfma_f32_16x16x32_f16(af[mi], bfr[ni], acc[mi][ni], 0, 0, 0);
        __syncthreads();
    }
#pragma unroll
    for (int mi = 0; mi < 4; ++mi) {
        int rbase = v0 + wm + mi * 16 + (lane >> 4) * 4;
#pragma unroll
        for (int ni = 0; ni < 4; ++ni) {
            int col = n0 + wn + ni * 16 + (lane & 15);
#pragma unroll
            for (int r = 0; r < 4; ++r) {
                int vr = rbase + r;
                if (vr < D_V) EG[(size_t)vr * D_G + col] = f2h(acc[mi][ni][r]);
            }
        }
    }
}

// ======================================================================
// lstm_seq: 64 WGs × 4 independent waves; counted-vmcnt pipelined h-loads
// in 8 half-tiles of 8 loads (4 buffers × 32 VGPRs, reissued after the
// mfma cluster that consumes them — WAR-safe in-order, schedule pinned by
// sched_barrier). EG gather issued post-poll, consumed at pointwise.
// Peak VGPR budget ≈ 350 (bq 128 + A 128 + acc 32 + ec 16 + misc) — no
// spill of pending-load asm outputs (the round-5 corruption mode).
// ======================================================================
#define MFMA_HALF(Aar, MT, KH)                                                         \
    _Pragma("unroll")                                                                  \
    for (int ks = 0; ks < 8; ++ks) {                                                   \
        acc[MT][0] = __builtin_amdgcn_mfma_f32_16x16x32_f16(Aar[ks], bq[0][(KH)*8+ks], acc[MT][0], 0, 0, 0); \
        acc[MT][1] = __builtin_amdgcn_mfma_f32_16x16x32_f16(Aar[ks], bq[1][(KH)*8+ks], acc[MT][1], 0, 0, 0); \
    }

#define LSTM_PHASE(T, TOKC, TOKN)                                                      \
do {                                                                                   \
    int tnext = (T) + 1; if (tnext > D_T - 1) tnext = D_T - 1;                         \
    issue_tok(abT + (size_t)tnext * D_B + b, TOKN);                                    \
    if ((T) > 0) {                                                                     \
        const int* fp = flags + wv * 64 + lane;                                        \
        int guard = 0;                                                                 \
        while (true) {                                                                 \
            int f = load_flag_llc(fp);   /* vmcnt(0) inside: drains TOKC too */        \
            if (__all(f >= (T))) break;                                                \
            if (++guard > (1 << 21)) break;                                            \
        }                                                                              \
        SBAR();                                                                        \
    }                                                                                  \
    f16x8 ec0, ec1, ec2, ec3;                                                          \
    issue_eg(EG + (size_t)(TOKC) * D_G + wg * 32, ec0, ec1, ec2, ec3);   /* +4 */      \
    const uint16_t* cur = hbuf + (size_t)((T) & 1) * (D_B * D_H);                      \
    const uint16_t* hb0 = cur + (size_t)((wv * 4 + 0) * 16 + (lane & 15)) * D_H + ((lane >> 4) * 8); \
    f16x8 A0[8], A1[8], A2[8], A3[8];                                                  \
    issue_h8(hb0,                A0);   /* m0 klo : +8 -> 12 */                        \
    issue_h8(hb0 + 256,          A1);   /* m0 khi : -> 20 */                           \
    issue_h8(hb0 + 16 * D_H,       A2); /* m1 klo : -> 28 */                           \
    issue_h8(hb0 + 16 * D_H + 256, A3); /* m1 khi : -> 36 (T=0: +1 tok) */             \
    f32x4 acc[4][2];                                                                   \
    _Pragma("unroll")                                                                  \
    for (int m = 0; m < 4; ++m) { acc[m][0] = (f32x4)0.0f; acc[m][1] = (f32x4)0.0f; }  \
    VWAIT(24);  /* retires [tok+]eg+A0 */                                              \
    MFMA_HALF(A0, 0, 0); SBAR();                                                       \
    issue_h8(hb0 + 32 * D_H,       A0); /* m2 klo -> 32 */                             \
    VWAIT(24);  /* A1 ready */                                                         \
    MFMA_HALF(A1, 0, 1); SBAR();                                                       \
    issue_h8(hb0 + 32 * D_H + 256, A1); /* m2 khi -> 32 */                             \
    VWAIT(24);  /* A2 ready */                                                         \
    MFMA_HALF(A2, 1, 0); SBAR();                                                       \
    issue_h8(hb0 + 48 * D_H,       A2); /* m3 klo -> 32 */                             \
    VWAIT(24);  /* A3 ready */                                                         \
    MFMA_HALF(A3, 1, 1); SBAR();                                                       \
    issue_h8(hb0 + 48 * D_H + 256, A3); /* m3 khi -> 32 */                             \
    VWAIT(24);  /* A0' (m2 klo) */                                                     \
    MFMA_HALF(A0, 2, 0); SBAR();                                                       \
    VWAIT(16);  /* A1' (m2 khi) */                                                     \
    MFMA_HALF(A1, 2, 1); SBAR();                                                       \
    VWAIT(8);   /* A2' (m3 klo) */                                                     \
    MFMA_HALF(A2, 3, 0); SBAR();                                                       \
    VWAIT(0);   /* A3' (m3 khi) */                                                     \
    MFMA_HALF(A3, 3, 1); SBAR();                                                       \
    /* epilogue: gate partial sums -> gfull (wave-private rows, no barrier) */         \
    _Pragma("unroll")                                                                  \
    for (int mtt = 0; mtt < 4; ++mtt) {                                                \
        int br = (wv * 4 + mtt) * 16 + (lane >> 4) * 4;                                \
        _Pragma("unroll")                                                              \
        for (int nt2 = 0; nt2 < 2; ++nt2) {                                            \
            int n = nt2 * 16 + (lane & 15);                                            \
            _Pragma("unroll")                                                          \
            for (int r = 0; r < 4; ++r) gfull[br + r][n] = acc[mtt][nt2][r];           \
        }                                                                              \
    }                                                                                  \
    /* pointwise: g = gfull + bias + EG(ec regs, retired at first VWAIT) */            \
    float ev[32];                                                                      \
    _Pragma("unroll")                                                                  \
    for (int i = 0; i < 8; ++i) { ev[i] = (float)ec0[i]; ev[8 + i] = (float)ec1[i];    \
                                  ev[16 + i] = (float)ec2[i]; ev[24 + i] = (float)ec3[i]; } \
    f16x8 vh;                                                                          \
    _Pragma("unroll")                                                                  \
    for (int j = 0; j < 8; ++j) {                                                      \
        float gi = gfull[b][j * 4 + 0] + bias_s[j * 4 + 0] + ev[j * 4 + 0];            \
        float gf = gfull[b][j * 4 + 1] + bias_s[j * 4 + 1] + ev[j * 4 + 1];            \
        float gg = gfull[b][j * 4 + 2] + bias_s[j * 4 + 2] + ev[j * 4 + 2];            \
        float go = gfull[b][j * 4 + 3] + bias_s[j * 4 + 3] + ev[j * 4 + 3];            \
        float c2 = sigm(gf) * creg[j] + sigm(gi) * tanh_fast(gg);                      \
        float h2 = sigm(go) * tanh_fast(c2);                                           \
        creg[j] = c2;                                                                  \
        float rm = fmaxf(rreg[j], h2);                                                 \
        if (((T) & 31) == 31) {                                                        \
            reps[(size_t)((T) >> 5) * (D_B * D_H) + (size_t)b * D_H + wg * 8 + j] = rm;\
            rm = -1e30f;                                                               \
        }                                                                              \
        rreg[j] = rm;                                                                  \
        vh[j] = (_Float16)h2;                                                          \
    }                                                                                  \
    uint16_t* dst = hbuf + (size_t)(((T) + 1) & 1) * (D_B * D_H) + (size_t)b * D_H + wg * 8; \
    store_h_nowait(dst, vh);                                                           \
    VWAIT(0);   /* drains reps stores + h store before publish */                      \
    if (lane == 0) store_flag_llc(flags + wv * 64 + wg, (T) + 1);                      \
} while (0)

__global__ __launch_bounds__(256, 1) void lstm_seq_kernel(
    const int* __restrict__ abT, const uint16_t* __restrict__ EG,
    const uint16_t* __restrict__ WhhP, const float* __restrict__ biasP,
    uint16_t* __restrict__ hbuf, int* __restrict__ flags,
    float* __restrict__ reps)
{
    const int wg = blockIdx.x;                 // 0..63
    const int tid = threadIdx.x, lane = tid & 63, wv = tid >> 6;
    __shared__ float gfull[256][33];
    __shared__ float bias_s[32];

    if (tid < 32) bias_s[tid] = biasP[wg * 32 + tid];

    float creg[8], rreg[8];
#pragma unroll
    for (int j = 0; j < 8; ++j) { creg[j] = 0.0f; rreg[j] = -1e30f; }

    // resident B fragments: Whh slice [32 rows][512 k] fp16 (cached loads)
    const uint16_t* Wp = WhhP + (size_t)wg * 32 * D_H;
    f16x8 bq[2][16];
#pragma unroll
    for (int nt = 0; nt < 2; ++nt)
#pragma unroll
        for (int ks = 0; ks < 16; ++ks)
            bq[nt][ks] = *(const f16x8*)(Wp + (size_t)(nt * 16 + (lane & 15)) * D_H + ks * 32 + ((lane >> 4) * 8));
    __syncthreads();   // bias_s ready; last barrier in the kernel

    const int b = tid;  // wave wv owns b in [wv*64, wv*64+64)

    int tok_a = abT[b];   // token for t=0 (compiler load, auto-waited)
    int tok_b;

    for (int t = 0; t < D_T; t += 2) {
        LSTM_PHASE(t,     tok_a, tok_b);
        LSTM_PHASE(t + 1, tok_b, tok_a);
    }
}

// ======================================================================
// predA (unchanged)
// ======================================================================
__global__ __launch_bounds__(256) void predA_kernel(
    const float* __restrict__ reps, const float* __restrict__ W1,
    const float* __restrict__ b1, float* __restrict__ A, float* __restrict__ A0)
{
    int gw = blockIdx.x * 4 + (threadIdx.x >> 6);
    int lane = threadIdx.x & 63;
    int s = gw >> 8, b = gw & 255;
    float accT[5] = {0, 0, 0, 0, 0};
    float acc0[5] = {0, 0, 0, 0, 0};
    for (int k = 0; k <= 2; ++k) {
        if (s - k < 0) break;
        const float* rp = reps + ((size_t)(s - k) * D_B + b) * D_H;
        const float* w  = W1 + (size_t)k * D_H * D_C;
        float part[5] = {0, 0, 0, 0, 0};
#pragma unroll
        for (int i = 0; i < 8; ++i) {
            int h = lane * 8 + i;
            float rv = rp[h];
#pragma unroll
            for (int c = 0; c < 5; ++c) part[c] += rv * w[h * 5 + c];
        }
#pragma unroll
        for (int c = 0; c < 5; ++c) { accT[c] += part[c]; if (k == 0) acc0[c] = part[c]; }
    }
#pragma unroll
    for (int m = 1; m < 64; m <<= 1)
#pragma unroll
        for (int c = 0; c < 5; ++c) {
            accT[c] += __shfl_xor(accT[c], m, 64);
            acc0[c] += __shfl_xor(acc0[c], m, 64);
        }
    if (lane == 0) {
#pragma unroll
        for (int c = 0; c < 5; ++c) A[((size_t)s * D_B + b) * D_C + c] = tanhf(accT[c] + b1[c]);
        if (s < 3)
#pragma unroll
            for (int c = 0; c < 5; ++c) A0[((size_t)s * D_B + b) * D_C + c] = tanhf(acc0[c] + b1[c]);
    }
}

// ======================================================================
// predOut (unchanged)
// ======================================================================
__global__ __launch_bounds__(256) void predOut_kernel(
    const float* __restrict__ A, const float* __restrict__ A0,
    const float* __restrict__ W2, const float* __restrict__ b2,
    float* __restrict__ out)
{
    int g = blockIdx.x * 256 + threadIdx.x;
    int b = g >> 4, s = g & 15;
    float v[5];
#pragma unroll
    for (int d = 0; d < 5; ++d) v[d] = b2[d];
    if (s < 3) {
        const float* Ar = A0 + ((size_t)s * D_B + b) * D_C;
#pragma unroll
        for (int c = 0; c < 5; ++c) {
            float a = Ar[c];
#pragma unroll
            for (int d = 0; d < 5; ++d) v[d] += a * W2[c * 5 + d];
        }
    } else {
        int i = s - 3;
        for (int tt = 0; tt < 4; ++tt) {
            const float* Ar = A + ((size_t)(tt + i) * D_B + b) * D_C;
            const float* w  = W2 + tt * 25;
#pragma unroll
            for (int c = 0; c < 5; ++c) {
                float a = Ar[c];
#pragma unroll
                for (int d = 0; d < 5; ++d) v[d] += a * w[c * 5 + d];
            }
        }
    }
    float m = v[0];
#pragma unroll
    for (int d = 1; d < 5; ++d) m = fmaxf(m, v[d]);
    float ssum = 0.0f;
#pragma unroll
    for (int d = 0; d < 5; ++d) ssum += expf(v[d] - m);
    float l = logf(ssum);
#pragma unroll
    for (int d = 0; d < 5; ++d) out[(size_t)b * 80 + d * 16 + s] = v[d] - m - l;
}

// ======================================================================
extern "C" void kernel_launch(void* const* d_in, const int* in_sizes, int n_in,
                              void* d_out, int out_size, void* d_ws, size_t ws_size,
                              hipStream_t stream)
{
    const int*   abstracts = (const int*)  d_in[0];
    const float* emb  = (const float*)d_in[1];
    const float* Wih  = (const float*)d_in[2];
    const float* Whh  = (const float*)d_in[3];
    const float* bih  = (const float*)d_in[4];
    const float* bhh  = (const float*)d_in[5];
    const float* W1   = (const float*)d_in[6];
    const float* b1   = (const float*)d_in[7];
    const float* W2   = (const float*)d_in[8];
    const float* b2   = (const float*)d_in[9];
    float* out = (float*)d_out;

    char* ws = (char*)d_ws;
    uint16_t* EG    = (uint16_t*)(ws + OFF_EG);
    uint16_t* embB  = (uint16_t*)(ws + OFF_EMB);
    uint16_t* WihP  = (uint16_t*)(ws + OFF_WIH);
    uint16_t* WhhP  = (uint16_t*)(ws + OFF_WHH);
    float*    biasP = (float*)   (ws + OFF_BIAS);
    uint16_t* hbuf  = (uint16_t*)(ws + OFF_HBUF);
    int*      flags = (int*)     (ws + OFF_FLAGS);
    float*    reps  = (float*)   (ws + OFF_REPS);
    float*    Abuf  = (float*)   (ws + OFF_A);
    float*    A0buf = (float*)   (ws + OFF_A0);
    int*      abT   = (int*)     (ws + OFF_ABT);

    prep_kernel<<<dim3(2048), dim3(256), 0, stream>>>(abstracts, emb, Wih, Whh, bih, bhh,
                                                      embB, WihP, WhhP, biasP, hbuf, flags, abT);
    egemm_kernel<<<dim3(16, 235), dim3(256), 0, stream>>>(embB, WihP, EG);
    lstm_seq_kernel<<<dim3(NWG), dim3(256), 0, stream>>>(abT, EG, WhhP, biasP,
                                                         hbuf, flags, reps);
    predA_kernel<<<dim3(1024), dim3(256), 0, stream>>>(reps, W1, b1, Abuf, A0buf);
    predOut_kernel<<<dim3(16), dim3(256), 0, stream>>>(Abuf, A0buf, W2, b2, out);
}

// Round 7
// 3005.405 us; speedup vs baseline: 1.9835x; 1.9835x over previous
//
#include <hip/hip_runtime.h>
#include <cstdint>
#include <cstddef>

// ---------------- types ----------------
typedef float    f32x4  __attribute__((ext_vector_type(4)));
typedef short    s16x8  __attribute__((ext_vector_type(8)));
typedef _Float16 f16x8  __attribute__((ext_vector_type(8)));
typedef uint16_t u16x4  __attribute__((ext_vector_type(4)));

// ---------------- problem dims ----------------
#define D_B 256
#define D_S 16
#define D_W 32
#define D_T 512      // S*W
#define D_V 30000
#define D_E 256
#define D_H 512
#define D_G 2048     // 4*H
#define D_C 5

// ---------------- workspace layout (bytes) ----------------
constexpr size_t OFF_EG    = 0;                                   // f16 [V][2048]  (perm cols)
constexpr size_t OFF_EMB   = OFF_EG   + (size_t)D_V * D_G * 2;    // f16 [V][256]
constexpr size_t OFF_WIH   = OFF_EMB  + (size_t)D_V * D_E * 2;    // f16 perm [2048][256]
constexpr size_t OFF_WHH   = OFF_WIH  + (size_t)D_G * D_E * 2;    // f16 perm [2048][512]
constexpr size_t OFF_BIAS  = OFF_WHH  + (size_t)D_G * D_H * 2;    // f32 perm [2048]
constexpr size_t OFF_HBUF  = OFF_BIAS + (size_t)D_G * 4;          // f16 [2][256KB] fragment-native
constexpr size_t OFF_FLAGS = OFF_HBUF + (size_t)2 * D_B * D_H * 2; // i32 [4 bg][64 rg]
constexpr size_t OFF_REPS  = OFF_FLAGS + (size_t)256 * 4;         // f32 [16][256][512]
constexpr size_t OFF_A     = OFF_REPS + (size_t)D_S * D_B * D_H * 4;  // f32 [16][256][5]
constexpr size_t OFF_A0    = OFF_A    + (size_t)D_S * D_B * D_C * 4;  // f32 [3][256][5]
constexpr size_t OFF_ABT   = OFF_A0   + (size_t)3 * D_B * D_C * 4;    // i32 [512][256]

// hbuf layout (per parity, 256KB): 16B units U = mrow*1024 + ks*64 + lane
//   holds h[row = mrow*16 + (lane&15)][k = ks*32 + (lane>>4)*8 .. +8]
// Consumer (bg, m-tile mtt): units (bg*4+mtt)*1024 + ks*64 + lane -> 1KB/instr
// Producer thread b, rowgroup rg: U = (b>>4)*1024 + (rg>>2)*64 + ((rg&3)<<4) + (b&15)

// ---------------- helpers ----------------
__device__ __forceinline__ uint16_t f2h(float f) {
    _Float16 h = (_Float16)f;
    return __builtin_bit_cast(uint16_t, h);
}
__device__ __forceinline__ float sigm(float x)  { return 1.0f / (1.0f + __expf(-x)); }
__device__ __forceinline__ float tanh_fast(float x) { return 1.0f - 2.0f / (__expf(2.0f * x) + 1.0f); }

// counted VMEM wait + scheduler fence (rule 18: consumers must not hoist)
#define VWAIT(N) do { asm volatile("s_waitcnt vmcnt(" #N ")" ::: "memory"); \
                      __builtin_amdgcn_sched_barrier(0); } while (0)
#define SBAR()   __builtin_amdgcn_sched_barrier(0)

// ---- LLC-coherent (cross-XCD) access: sc0 sc1 bypasses L1+L2 per access.
__device__ __forceinline__ int load_flag_llc(const int* p) {
    int v;
    asm volatile("global_load_dword %0, %1, off sc0 sc1\n\ts_waitcnt vmcnt(0)"
                 : "=v"(v) : "v"(p) : "memory");
    return v;
}
__device__ __forceinline__ void store_flag_llc(int* p, int v) {
    asm volatile("global_store_dword %0, %1, off sc0 sc1" :: "v"(p), "v"(v) : "memory");
}
__device__ __forceinline__ void store_dword_llc(int* p, int v) {
    asm volatile("global_store_dword %0, %1, off sc0 sc1" :: "v"(p), "v"(v) : "memory");
}
__device__ __forceinline__ void store16_llc(void* p, f32x4 v) {
    asm volatile("global_store_dwordx4 %0, %1, off sc0 sc1" :: "v"(p), "v"(v) : "memory");
}
__device__ __forceinline__ void store_h_nowait(uint16_t* p, f16x8 v) {
    asm volatile("global_store_dwordx4 %0, %1, off sc0 sc1" :: "v"(p), "v"(v) : "memory");
}
// cached (L1/L2) token prefetch, no wait — drained by the next poll's vmcnt(0)
__device__ __forceinline__ void issue_tok(const int* p, int& v) {
    asm volatile("global_load_dword %0, %1, off" : "=&v"(v) : "v"(p) : "memory");
}
// cached EG prefetch (64B slice), no wait; issued AFTER h-loads so it never
// gates an MFMA VWAIT (vmcnt retires in issue order)
__device__ __forceinline__ void issue_eg(const uint16_t* p, f16x8& a, f16x8& b2,
                                         f16x8& c, f16x8& d) {
    asm volatile(
        "global_load_dwordx4 %0, %4, off\n\t"
        "global_load_dwordx4 %1, %4, off offset:16\n\t"
        "global_load_dwordx4 %2, %4, off offset:32\n\t"
        "global_load_dwordx4 %3, %4, off offset:48"
        : "=&v"(a), "=&v"(b2), "=&v"(c), "=&v"(d)
        : "v"(p) : "memory");
}
// 8 coalesced 1KB LLC loads = one (m-tile, k-half), NO wait (pipelined).
// base in halves; 13-bit imm offset caps at 4095B so split across two bases.
__device__ __forceinline__ void issue_h8(const uint16_t* base, f16x8* A) {
    const uint16_t* base2 = base + 2048;   // +4KB
    asm volatile(
        "global_load_dwordx4 %0, %8, off sc0 sc1\n\t"
        "global_load_dwordx4 %1, %8, off offset:1024 sc0 sc1\n\t"
        "global_load_dwordx4 %2, %8, off offset:2048 sc0 sc1\n\t"
        "global_load_dwordx4 %3, %8, off offset:3072 sc0 sc1\n\t"
        "global_load_dwordx4 %4, %9, off sc0 sc1\n\t"
        "global_load_dwordx4 %5, %9, off offset:1024 sc0 sc1\n\t"
        "global_load_dwordx4 %6, %9, off offset:2048 sc0 sc1\n\t"
        "global_load_dwordx4 %7, %9, off offset:3072 sc0 sc1"
        : "=&v"(A[0]), "=&v"(A[1]), "=&v"(A[2]), "=&v"(A[3]),
          "=&v"(A[4]), "=&v"(A[5]), "=&v"(A[6]), "=&v"(A[7])
        : "v"(base), "v"(base2) : "memory");
}

// ======================================================================
// prep (unchanged)
// ======================================================================
__global__ __launch_bounds__(256) void prep_kernel(
    const int* __restrict__ abstracts,
    const float* __restrict__ emb, const float* __restrict__ Wih,
    const float* __restrict__ Whh, const float* __restrict__ bih,
    const float* __restrict__ bhh,
    uint16_t* __restrict__ embB, uint16_t* __restrict__ WihP,
    uint16_t* __restrict__ WhhP, float* __restrict__ biasP,
    uint16_t* __restrict__ hbuf0, int* __restrict__ flags,
    int* __restrict__ abT)
{
    const long NA = (long)D_V * D_E / 4;
    const long NB = (long)D_G * D_E / 4;
    const long NC = (long)D_G * D_H / 4;
    const long ND = D_G;
    const long NE = (long)D_B * D_H / 8;
    const long NF = 256;
    const long NG = (long)D_T * D_B;
    const long TOT = NA + NB + NC + ND + NE + NF + NG;
    long stride = (long)gridDim.x * blockDim.x;
    for (long i = (long)blockIdx.x * blockDim.x + threadIdx.x; i < TOT; i += stride) {
        if (i < NA) {
            f32x4 v = ((const f32x4*)emb)[i];
            u16x4 o = { f2h(v[0]), f2h(v[1]), f2h(v[2]), f2h(v[3]) };
            ((u16x4*)embB)[i] = o;
        } else if (i < NA + NB) {
            long j = i - NA; long flat = j * 4;
            int r = (int)(flat >> 8), e0 = (int)(flat & 255);
            int p = ((r & 511) << 2) | (r >> 9);
            f32x4 v = ((const f32x4*)Wih)[j];
            u16x4 o = { f2h(v[0]), f2h(v[1]), f2h(v[2]), f2h(v[3]) };
            *(u16x4*)(WihP + (size_t)p * D_E + e0) = o;
        } else if (i < NA + NB + NC) {
            long j = i - NA - NB; long flat = j * 4;
            int r = (int)(flat >> 9), k0 = (int)(flat & 511);
            int p = ((r & 511) << 2) | (r >> 9);
            f32x4 v = ((const f32x4*)Whh)[j];
            u16x4 o = { f2h(v[0]), f2h(v[1]), f2h(v[2]), f2h(v[3]) };
            *(u16x4*)(WhhP + (size_t)p * D_H + k0) = o;
        } else if (i < NA + NB + NC + ND) {
            int p = (int)(i - NA - NB - NC);
            int r = ((p & 3) << 9) | (p >> 2);
            biasP[p] = bih[r] + bhh[r];
        } else if (i < NA + NB + NC + ND + NE) {
            long j = i - NA - NB - NC - ND;
            f32x4 z = (f32x4)0.0f;
            store16_llc(hbuf0 + j * 8, z);
        } else if (i < NA + NB + NC + ND + NE + NF) {
            long j = i - NA - NB - NC - ND - NE;
            store_dword_llc(flags + j, 0);
        } else {
            long j = i - NA - NB - NC - ND - NE - NF;
            int t = (int)(j >> 8), b = (int)(j & 255);
            abT[(size_t)t * D_B + b] = abstracts[(size_t)b * D_T + t];
        }
    }
    asm volatile("s_waitcnt vmcnt(0)" ::: "memory");  // drain LLC stores
}

// ======================================================================
// egemm (unchanged)
// ======================================================================
__global__ __launch_bounds__(256) void egemm_kernel(
    const uint16_t* __restrict__ embB, const uint16_t* __restrict__ WihP,
    uint16_t* __restrict__ EG)
{
    int nt = blockIdx.x;
    int mt = blockIdx.y;
    int tid = threadIdx.x, lane = tid & 63, wv = tid >> 6;
    int v0 = mt * 128, n0 = nt * 128;
    __shared__ uint16_t As[128][40];
    __shared__ uint16_t Bs[128][40];
    f32x4 acc[4][4];
#pragma unroll
    for (int a = 0; a < 4; ++a)
#pragma unroll
        for (int bb = 0; bb < 4; ++bb) acc[a][bb] = (f32x4)0.0f;
    int wm = (wv >> 1) * 64, wn = (wv & 1) * 64;
    int row = tid >> 1, half = tid & 1;
    for (int kb = 0; kb < 8; ++kb) {
        int k0 = kb * 32;
        int vrow = v0 + row; if (vrow > D_V - 1) vrow = D_V - 1;
        const s16x8* pa = (const s16x8*)(embB + (size_t)vrow * D_E + k0 + half * 16);
        *(s16x8*)&As[row][half * 16]     = pa[0];
        *(s16x8*)&As[row][half * 16 + 8] = pa[1];
        const s16x8* pb = (const s16x8*)(WihP + (size_t)(n0 + row) * D_E + k0 + half * 16);
        *(s16x8*)&Bs[row][half * 16]     = pb[0];
        *(s16x8*)&Bs[row][half * 16 + 8] = pb[1];
        __syncthreads();
        int krow = (lane >> 4) * 8;
        f16x8 af[4], bfr[4];
#pragma unroll
        for (int i = 0; i < 4; ++i) af[i]  = *(const f16x8*)&As[wm + i * 16 + (lane & 15)][krow];
#pragma unroll
        for (int i = 0; i < 4; ++i) bfr[i] = *(const f16x8*)&Bs[wn + i * 16 + (lane & 15)][krow];
#pragma unroll
        for (int mi = 0; mi < 4; ++mi)
#pragma unroll
            for (int ni = 0; ni < 4; ++ni)
                acc[mi][ni] = __builtin_amdgcn_mfma_f32_16x16x32_f16(af[mi], bfr[ni], acc[mi][ni], 0, 0, 0);
        __syncthreads();
    }
#pragma unroll
    for (int mi = 0; mi < 4; ++mi) {
        int rbase = v0 + wm + mi * 16 + (lane >> 4) * 4;
#pragma unroll
        for (int ni = 0; ni < 4; ++ni) {
            int col = n0 + wn + ni * 16 + (lane & 15);
#pragma unroll
            for (int r = 0; r < 4; ++r) {
                int vr = rbase + r;
                if (vr < D_V) EG[(size_t)vr * D_G + col] = f2h(acc[mi][ni][r]);
            }
        }
    }
}

// ======================================================================
// lstm_seq: 256 WGs × 1 wave. WG (rg, bg): gate rowgroup rg (32 perm rows,
// Whh slice in VGPRs) × batch group bg (64 rows). The 4 bg chains are
// independent (poll only own bg's 64 flags). h exchanged via LLC in a
// fragment-native layout -> fully coalesced 1KB loads / 256B store runs.
// vmcnt ladder: h-loads issued before EG so EG never gates MFMA.
// ======================================================================
#define MFMA_HALF(Aar, MT, KH)                                                         \
    _Pragma("unroll")                                                                  \
    for (int ks = 0; ks < 8; ++ks) {                                                   \
        acc[MT][0] = __builtin_amdgcn_mfma_f32_16x16x32_f16(Aar[ks], bq[0][(KH)*8+ks], acc[MT][0], 0, 0, 0); \
        acc[MT][1] = __builtin_amdgcn_mfma_f32_16x16x32_f16(Aar[ks], bq[1][(KH)*8+ks], acc[MT][1], 0, 0, 0); \
    }

#define LSTM_PHASE(T, TOKC, TOKN)                                                      \
do {                                                                                   \
    int tnext = (T) + 1; if (tnext > D_T - 1) tnext = D_T - 1;                         \
    issue_tok(abT + (size_t)tnext * D_B + b, TOKN);                                    \
    if ((T) > 0) {                                                                     \
        const int* fp = flags + bg * 64 + lane;                                        \
        int guard = 0;                                                                 \
        while (true) {                                                                 \
            int f = load_flag_llc(fp);   /* vmcnt(0) inside: drains TOKC too */        \
            if (__all(f >= (T))) break;                                                \
            if (++guard > (1 << 21)) break;                                            \
        }                                                                              \
        SBAR();                                                                        \
    }                                                                                  \
    const uint16_t* cur = hbuf + (size_t)((T) & 1) * (D_B * D_H);                      \
    const uint16_t* hb = cur + (size_t)bg * 4 * 8192 + lane * 8;                       \
    f16x8 A0[8], A1[8], A2[8], A3[8];                                                  \
    issue_h8(hb,                 A0);   /* m0 klo */                                   \
    issue_h8(hb + 4096,          A1);   /* m0 khi */                                   \
    issue_h8(hb + 8192,          A2);   /* m1 klo */                                   \
    issue_h8(hb + 12288,         A3);   /* m1 khi */                                   \
    f16x8 ec0, ec1, ec2, ec3;                                                          \
    issue_eg(EG + (size_t)(TOKC) * D_G + rg * 32, ec0, ec1, ec2, ec3);                 \
    f32x4 acc[4][2];                                                                   \
    _Pragma("unroll")                                                                  \
    for (int m = 0; m < 4; ++m) { acc[m][0] = (f32x4)0.0f; acc[m][1] = (f32x4)0.0f; }  \
    VWAIT(28); MFMA_HALF(A0, 0, 0); SBAR();                                            \
    issue_h8(hb + 16384, A0);           /* m2 klo */                                   \
    VWAIT(28); MFMA_HALF(A1, 0, 1); SBAR();                                            \
    issue_h8(hb + 20480, A1);           /* m2 khi */                                   \
    VWAIT(28); MFMA_HALF(A2, 1, 0); SBAR();                                            \
    issue_h8(hb + 24576, A2);           /* m3 klo */                                   \
    VWAIT(28); MFMA_HALF(A3, 1, 1); SBAR();                                            \
    issue_h8(hb + 28672, A3);           /* m3 khi */                                   \
    VWAIT(24); MFMA_HALF(A0, 2, 0); SBAR();   /* retires eg + m2klo */                 \
    VWAIT(16); MFMA_HALF(A1, 2, 1); SBAR();                                            \
    VWAIT(8);  MFMA_HALF(A2, 3, 0); SBAR();                                            \
    VWAIT(0);  MFMA_HALF(A3, 3, 1); SBAR();                                            \
    /* epilogue: acc -> gfull (local batch rows 0..63) */                              \
    _Pragma("unroll")                                                                  \
    for (int mtt = 0; mtt < 4; ++mtt) {                                                \
        int br = mtt * 16 + (lane >> 4) * 4;                                           \
        _Pragma("unroll")                                                              \
        for (int nt2 = 0; nt2 < 2; ++nt2) {                                            \
            int n = nt2 * 16 + (lane & 15);                                            \
            _Pragma("unroll")                                                          \
            for (int r = 0; r < 4; ++r) gfull[br + r][n] = acc[mtt][nt2][r];           \
        }                                                                              \
    }                                                                                  \
    __syncthreads();   /* single wave: lgkmcnt drain for cross-lane LDS */             \
    /* pointwise: g = gfull + bias + EG */                                             \
    float ev[32];                                                                      \
    _Pragma("unroll")                                                                  \
    for (int i = 0; i < 8; ++i) { ev[i] = (float)ec0[i]; ev[8 + i] = (float)ec1[i];    \
                                  ev[16 + i] = (float)ec2[i]; ev[24 + i] = (float)ec3[i]; } \
    f16x8 vh;                                                                          \
    _Pragma("unroll")                                                                  \
    for (int j = 0; j < 8; ++j) {                                                      \
        float gi = gfull[lane][j * 4 + 0] + bias_s[j * 4 + 0] + ev[j * 4 + 0];         \
        float gf = gfull[lane][j * 4 + 1] + bias_s[j * 4 + 1] + ev[j * 4 + 1];         \
        float gg = gfull[lane][j * 4 + 2] + bias_s[j * 4 + 2] + ev[j * 4 + 2];         \
        float go = gfull[lane][j * 4 + 3] + bias_s[j * 4 + 3] + ev[j * 4 + 3];         \
        float c2 = sigm(gf) * creg[j] + sigm(gi) * tanh_fast(gg);                      \
        float h2 = sigm(go) * tanh_fast(c2);                                           \
        creg[j] = c2;                                                                  \
        float rm = fmaxf(rreg[j], h2);                                                 \
        if (((T) & 31) == 31) {                                                        \
            reps[(size_t)((T) >> 5) * (D_B * D_H) + (size_t)b * D_H + rg * 8 + j] = rm;\
            rm = -1e30f;                                                               \
        }                                                                              \
        rreg[j] = rm;                                                                  \
        vh[j] = (_Float16)h2;                                                          \
    }                                                                                  \
    uint16_t* nxt = hbuf + (size_t)(((T) + 1) & 1) * (D_B * D_H);                      \
    store_h_nowait(nxt + (size_t)U * 8, vh);                                           \
    VWAIT(0);   /* drains reps stores + h store before publish */                      \
    if (lane == 0) store_flag_llc(flags + bg * 64 + rg, (T) + 1);                      \
    __syncthreads();  /* keep the wave's LDS phases aligned across unroll */           \
} while (0)

__global__ __launch_bounds__(64, 1) void lstm_seq_kernel(
    const int* __restrict__ abT, const uint16_t* __restrict__ EG,
    const uint16_t* __restrict__ WhhP, const float* __restrict__ biasP,
    uint16_t* __restrict__ hbuf, int* __restrict__ flags,
    float* __restrict__ reps)
{
    const int bid = blockIdx.x;
    const int rg = bid & 63;          // gate rowgroup 0..63
    const int bg = bid >> 6;          // batch group 0..3
    const int lane = threadIdx.x;     // 0..63
    __shared__ float gfull[64][33];
    __shared__ float bias_s[32];

    if (lane < 32) bias_s[lane] = biasP[rg * 32 + lane];

    float creg[8], rreg[8];
#pragma unroll
    for (int j = 0; j < 8; ++j) { creg[j] = 0.0f; rreg[j] = -1e30f; }

    // resident B fragments: Whh slice [32 rows][512 k] fp16 (cached loads)
    const uint16_t* Wp = WhhP + (size_t)rg * 32 * D_H;
    f16x8 bq[2][16];
#pragma unroll
    for (int nt = 0; nt < 2; ++nt)
#pragma unroll
        for (int ks = 0; ks < 16; ++ks)
            bq[nt][ks] = *(const f16x8*)(Wp + (size_t)(nt * 16 + (lane & 15)) * D_H + ks * 32 + ((lane >> 4) * 8));
    __syncthreads();

    const int b = bg * 64 + lane;     // global batch row
    const int U = ((b >> 4) << 10) + ((rg >> 2) << 6) + ((rg & 3) << 4) + (b & 15);

    int tok_a = abT[b];   // token for t=0 (compiler load, auto-waited)
    int tok_b;

    for (int t = 0; t < D_T; t += 2) {
        LSTM_PHASE(t,     tok_a, tok_b);
        LSTM_PHASE(t + 1, tok_b, tok_a);
    }
}

// ======================================================================
// predA (unchanged)
// ======================================================================
__global__ __launch_bounds__(256) void predA_kernel(
    const float* __restrict__ reps, const float* __restrict__ W1,
    const float* __restrict__ b1, float* __restrict__ A, float* __restrict__ A0)
{
    int gw = blockIdx.x * 4 + (threadIdx.x >> 6);
    int lane = threadIdx.x & 63;
    int s = gw >> 8, b = gw & 255;
    float accT[5] = {0, 0, 0, 0, 0};
    float acc0[5] = {0, 0, 0, 0, 0};
    for (int k = 0; k <= 2; ++k) {
        if (s - k < 0) break;
        const float* rp = reps + ((size_t)(s - k) * D_B + b) * D_H;
        const float* w  = W1 + (size_t)k * D_H * D_C;
        float part[5] = {0, 0, 0, 0, 0};
#pragma unroll
        for (int i = 0; i < 8; ++i) {
            int h = lane * 8 + i;
            float rv = rp[h];
#pragma unroll
            for (int c = 0; c < 5; ++c) part[c] += rv * w[h * 5 + c];
        }
#pragma unroll
        for (int c = 0; c < 5; ++c) { accT[c] += part[c]; if (k == 0) acc0[c] = part[c]; }
    }
#pragma unroll
    for (int m = 1; m < 64; m <<= 1)
#pragma unroll
        for (int c = 0; c < 5; ++c) {
            accT[c] += __shfl_xor(accT[c], m, 64);
            acc0[c] += __shfl_xor(acc0[c], m, 64);
        }
    if (lane == 0) {
#pragma unroll
        for (int c = 0; c < 5; ++c) A[((size_t)s * D_B + b) * D_C + c] = tanhf(accT[c] + b1[c]);
        if (s < 3)
#pragma unroll
            for (int c = 0; c < 5; ++c) A0[((size_t)s * D_B + b) * D_C + c] = tanhf(acc0[c] + b1[c]);
    }
}

// ======================================================================
// predOut (unchanged)
// ======================================================================
__global__ __launch_bounds__(256) void predOut_kernel(
    const float* __restrict__ A, const float* __restrict__ A0,
    const float* __restrict__ W2, const float* __restrict__ b2,
    float* __restrict__ out)
{
    int g = blockIdx.x * 256 + threadIdx.x;
    int b = g >> 4, s = g & 15;
    float v[5];
#pragma unroll
    for (int d = 0; d < 5; ++d) v[d] = b2[d];
    if (s < 3) {
        const float* Ar = A0 + ((size_t)s * D_B + b) * D_C;
#pragma unroll
        for (int c = 0; c < 5; ++c) {
            float a = Ar[c];
#pragma unroll
            for (int d = 0; d < 5; ++d) v[d] += a * W2[c * 5 + d];
        }
    } else {
        int i = s - 3;
        for (int tt = 0; tt < 4; ++tt) {
            const float* Ar = A + ((size_t)(tt + i) * D_B + b) * D_C;
            const float* w  = W2 + tt * 25;
#pragma unroll
            for (int c = 0; c < 5; ++c) {
                float a = Ar[c];
#pragma unroll
                for (int d = 0; d < 5; ++d) v[d] += a * w[c * 5 + d];
            }
        }
    }
    float m = v[0];
#pragma unroll
    for (int d = 1; d < 5; ++d) m = fmaxf(m, v[d]);
    float ssum = 0.0f;
#pragma unroll
    for (int d = 0; d < 5; ++d) ssum += expf(v[d] - m);
    float l = logf(ssum);
#pragma unroll
    for (int d = 0; d < 5; ++d) out[(size_t)b * 80 + d * 16 + s] = v[d] - m - l;
}

// ======================================================================
extern "C" void kernel_launch(void* const* d_in, const int* in_sizes, int n_in,
                              void* d_out, int out_size, void* d_ws, size_t ws_size,
                              hipStream_t stream)
{
    const int*   abstracts = (const int*)  d_in[0];
    const float* emb  = (const float*)d_in[1];
    const float* Wih  = (const float*)d_in[2];
    const float* Whh  = (const float*)d_in[3];
    const float* bih  = (const float*)d_in[4];
    const float* bhh  = (const float*)d_in[5];
    const float* W1   = (const float*)d_in[6];
    const float* b1   = (const float*)d_in[7];
    const float* W2   = (const float*)d_in[8];
    const float* b2   = (const float*)d_in[9];
    float* out = (float*)d_out;

    char* ws = (char*)d_ws;
    uint16_t* EG    = (uint16_t*)(ws + OFF_EG);
    uint16_t* embB  = (uint16_t*)(ws + OFF_EMB);
    uint16_t* WihP  = (uint16_t*)(ws + OFF_WIH);
    uint16_t* WhhP  = (uint16_t*)(ws + OFF_WHH);
    float*    biasP = (float*)   (ws + OFF_BIAS);
    uint16_t* hbuf  = (uint16_t*)(ws + OFF_HBUF);
    int*      flags = (int*)     (ws + OFF_FLAGS);
    float*    reps  = (float*)   (ws + OFF_REPS);
    float*    Abuf  = (float*)   (ws + OFF_A);
    float*    A0buf = (float*)   (ws + OFF_A0);
    int*      abT   = (int*)     (ws + OFF_ABT);

    prep_kernel<<<dim3(2048), dim3(256), 0, stream>>>(abstracts, emb, Wih, Whh, bih, bhh,
                                                      embB, WihP, WhhP, biasP, hbuf, flags, abT);
    egemm_kernel<<<dim3(16, 235), dim3(256), 0, stream>>>(embB, WihP, EG);
    lstm_seq_kernel<<<dim3(256), dim3(64), 0, stream>>>(abT, EG, WhhP, biasP,
                                                        hbuf, flags, reps);
    predA_kernel<<<dim3(1024), dim3(256), 0, stream>>>(reps, W1, b1, Abuf, A0buf);
    predOut_kernel<<<dim3(16), dim3(256), 0, stream>>>(Abuf, A0buf, W2, b2, out);
}

// Round 8
// 2680.518 us; speedup vs baseline: 2.2239x; 1.1212x over previous
//
#include <hip/hip_runtime.h>
#include <cstdint>
#include <cstddef>

// ---------------- types ----------------
typedef float    f32x4  __attribute__((ext_vector_type(4)));
typedef short    s16x8  __attribute__((ext_vector_type(8)));
typedef _Float16 f16x8  __attribute__((ext_vector_type(8)));
typedef uint16_t u16x4  __attribute__((ext_vector_type(4)));

// ---------------- problem dims ----------------
#define D_B 256
#define D_S 16
#define D_W 32
#define D_T 512      // S*W
#define D_V 30000
#define D_E 256
#define D_H 512
#define D_G 2048     // 4*H
#define D_C 5

// ---------------- workspace layout (bytes) ----------------
constexpr size_t OFF_EG    = 0;                                   // f16 [V][2048]  (perm cols)
constexpr size_t OFF_EMB   = OFF_EG   + (size_t)D_V * D_G * 2;    // f16 [V][256]
constexpr size_t OFF_WIH   = OFF_EMB  + (size_t)D_V * D_E * 2;    // f16 perm [2048][256]
constexpr size_t OFF_WHH   = OFF_WIH  + (size_t)D_G * D_E * 2;    // f16 perm [2048][512]
constexpr size_t OFF_BIAS  = OFF_WHH  + (size_t)D_G * D_H * 2;    // f32 perm [2048]
constexpr size_t OFF_HBUF  = OFF_BIAS + (size_t)D_G * 4;          // f16 [2][256KB] fragment-native
constexpr size_t OFF_FLAGS = OFF_HBUF + (size_t)2 * D_B * D_H * 2; // i32 [256]; ctr[bg] at bg*32
constexpr size_t OFF_REPS  = OFF_FLAGS + (size_t)256 * 4;         // f32 [16][256][512]
constexpr size_t OFF_A     = OFF_REPS + (size_t)D_S * D_B * D_H * 4;  // f32 [16][256][5]
constexpr size_t OFF_A0    = OFF_A    + (size_t)D_S * D_B * D_C * 4;  // f32 [3][256][5]
constexpr size_t OFF_ABT   = OFF_A0   + (size_t)3 * D_B * D_C * 4;    // i32 [512][256]

// hbuf layout (per parity, 256KB): 16B units U = mrow*1024 + ks*64 + lane
//   holds h[row = mrow*16 + (lane&15)][k = ks*32 + (lane>>4)*8 .. +8]

// ---------------- helpers ----------------
__device__ __forceinline__ uint16_t f2h(float f) {
    _Float16 h = (_Float16)f;
    return __builtin_bit_cast(uint16_t, h);
}
__device__ __forceinline__ float sigm(float x)  { return 1.0f / (1.0f + __expf(-x)); }
__device__ __forceinline__ float tanh_fast(float x) { return 1.0f - 2.0f / (__expf(2.0f * x) + 1.0f); }

// counted VMEM wait + scheduler fence (rule 18: consumers must not hoist)
#define VWAIT(N) do { asm volatile("s_waitcnt vmcnt(" #N ")" ::: "memory"); \
                      __builtin_amdgcn_sched_barrier(0); } while (0)
#define SBAR()   __builtin_amdgcn_sched_barrier(0)

// ---- LLC-coherent (cross-XCD) access: sc0 sc1 bypasses L1+L2 per access.
__device__ __forceinline__ int load_flag_llc(const int* p) {
    int v;
    asm volatile("global_load_dword %0, %1, off sc0 sc1\n\ts_waitcnt vmcnt(0)"
                 : "=v"(v) : "v"(p) : "memory");
    return v;
}
__device__ __forceinline__ void store_dword_llc(int* p, int v) {
    asm volatile("global_store_dword %0, %1, off sc0 sc1" :: "v"(p), "v"(v) : "memory");
}
__device__ __forceinline__ void store16_llc(void* p, f32x4 v) {
    asm volatile("global_store_dwordx4 %0, %1, off sc0 sc1" :: "v"(p), "v"(v) : "memory");
}
__device__ __forceinline__ void store_h_nowait(uint16_t* p, f16x8 v) {
    asm volatile("global_store_dwordx4 %0, %1, off sc0 sc1" :: "v"(p), "v"(v) : "memory");
}
// cached (L1/L2) token prefetch, no wait — drained by the poll's vmcnt(0)
__device__ __forceinline__ void issue_tok(const int* p, int& v) {
    asm volatile("global_load_dword %0, %1, off" : "=&v"(v) : "v"(p) : "memory");
}
// cached EG prefetch (64B slice), no wait; issued BEFORE the poll so its
// latency hides under the flag wait (poll's vmcnt(0) drains it).
__device__ __forceinline__ void issue_eg(const uint16_t* p, f16x8& a, f16x8& b2,
                                         f16x8& c, f16x8& d) {
    asm volatile(
        "global_load_dwordx4 %0, %4, off\n\t"
        "global_load_dwordx4 %1, %4, off offset:16\n\t"
        "global_load_dwordx4 %2, %4, off offset:32\n\t"
        "global_load_dwordx4 %3, %4, off offset:48"
        : "=&v"(a), "=&v"(b2), "=&v"(c), "=&v"(d)
        : "v"(p) : "memory");
}
// 8 coalesced 1KB LLC loads = one (m-tile, k-half), NO wait (pipelined).
__device__ __forceinline__ void issue_h8(const uint16_t* base, f16x8* A) {
    const uint16_t* base2 = base + 2048;   // +4KB
    asm volatile(
        "global_load_dwordx4 %0, %8, off sc0 sc1\n\t"
        "global_load_dwordx4 %1, %8, off offset:1024 sc0 sc1\n\t"
        "global_load_dwordx4 %2, %8, off offset:2048 sc0 sc1\n\t"
        "global_load_dwordx4 %3, %8, off offset:3072 sc0 sc1\n\t"
        "global_load_dwordx4 %4, %9, off sc0 sc1\n\t"
        "global_load_dwordx4 %5, %9, off offset:1024 sc0 sc1\n\t"
        "global_load_dwordx4 %6, %9, off offset:2048 sc0 sc1\n\t"
        "global_load_dwordx4 %7, %9, off offset:3072 sc0 sc1"
        : "=&v"(A[0]), "=&v"(A[1]), "=&v"(A[2]), "=&v"(A[3]),
          "=&v"(A[4]), "=&v"(A[5]), "=&v"(A[6]), "=&v"(A[7])
        : "v"(base), "v"(base2) : "memory");
}

// ======================================================================
// prep (unchanged)
// ======================================================================
__global__ __launch_bounds__(256) void prep_kernel(
    const int* __restrict__ abstracts,
    const float* __restrict__ emb, const float* __restrict__ Wih,
    const float* __restrict__ Whh, const float* __restrict__ bih,
    const float* __restrict__ bhh,
    uint16_t* __restrict__ embB, uint16_t* __restrict__ WihP,
    uint16_t* __restrict__ WhhP, float* __restrict__ biasP,
    uint16_t* __restrict__ hbuf0, int* __restrict__ flags,
    int* __restrict__ abT)
{
    const long NA = (long)D_V * D_E / 4;
    const long NB = (long)D_G * D_E / 4;
    const long NC = (long)D_G * D_H / 4;
    const long ND = D_G;
    const long NE = (long)D_B * D_H / 8;
    const long NF = 256;
    const long NG = (long)D_T * D_B;
    const long TOT = NA + NB + NC + ND + NE + NF + NG;
    long stride = (long)gridDim.x * blockDim.x;
    for (long i = (long)blockIdx.x * blockDim.x + threadIdx.x; i < TOT; i += stride) {
        if (i < NA) {
            f32x4 v = ((const f32x4*)emb)[i];
            u16x4 o = { f2h(v[0]), f2h(v[1]), f2h(v[2]), f2h(v[3]) };
            ((u16x4*)embB)[i] = o;
        } else if (i < NA + NB) {
            long j = i - NA; long flat = j * 4;
            int r = (int)(flat >> 8), e0 = (int)(flat & 255);
            int p = ((r & 511) << 2) | (r >> 9);
            f32x4 v = ((const f32x4*)Wih)[j];
            u16x4 o = { f2h(v[0]), f2h(v[1]), f2h(v[2]), f2h(v[3]) };
            *(u16x4*)(WihP + (size_t)p * D_E + e0) = o;
        } else if (i < NA + NB + NC) {
            long j = i - NA - NB; long flat = j * 4;
            int r = (int)(flat >> 9), k0 = (int)(flat & 511);
            int p = ((r & 511) << 2) | (r >> 9);
            f32x4 v = ((const f32x4*)Whh)[j];
            u16x4 o = { f2h(v[0]), f2h(v[1]), f2h(v[2]), f2h(v[3]) };
            *(u16x4*)(WhhP + (size_t)p * D_H + k0) = o;
        } else if (i < NA + NB + NC + ND) {
            int p = (int)(i - NA - NB - NC);
            int r = ((p & 3) << 9) | (p >> 2);
            biasP[p] = bih[r] + bhh[r];
        } else if (i < NA + NB + NC + ND + NE) {
            long j = i - NA - NB - NC - ND;
            f32x4 z = (f32x4)0.0f;
            store16_llc(hbuf0 + j * 8, z);
        } else if (i < NA + NB + NC + ND + NE + NF) {
            long j = i - NA - NB - NC - ND - NE;
            store_dword_llc(flags + j, 0);
        } else {
            long j = i - NA - NB - NC - ND - NE - NF;
            int t = (int)(j >> 8), b = (int)(j & 255);
            abT[(size_t)t * D_B + b] = abstracts[(size_t)b * D_T + t];
        }
    }
    asm volatile("s_waitcnt vmcnt(0)" ::: "memory");  // drain LLC stores
}

// ======================================================================
// egemm (unchanged)
// ======================================================================
__global__ __launch_bounds__(256) void egemm_kernel(
    const uint16_t* __restrict__ embB, const uint16_t* __restrict__ WihP,
    uint16_t* __restrict__ EG)
{
    int nt = blockIdx.x;
    int mt = blockIdx.y;
    int tid = threadIdx.x, lane = tid & 63, wv = tid >> 6;
    int v0 = mt * 128, n0 = nt * 128;
    __shared__ uint16_t As[128][40];
    __shared__ uint16_t Bs[128][40];
    f32x4 acc[4][4];
#pragma unroll
    for (int a = 0; a < 4; ++a)
#pragma unroll
        for (int bb = 0; bb < 4; ++bb) acc[a][bb] = (f32x4)0.0f;
    int wm = (wv >> 1) * 64, wn = (wv & 1) * 64;
    int row = tid >> 1, half = tid & 1;
    for (int kb = 0; kb < 8; ++kb) {
        int k0 = kb * 32;
        int vrow = v0 + row; if (vrow > D_V - 1) vrow = D_V - 1;
        const s16x8* pa = (const s16x8*)(embB + (size_t)vrow * D_E + k0 + half * 16);
        *(s16x8*)&As[row][half * 16]     = pa[0];
        *(s16x8*)&As[row][half * 16 + 8] = pa[1];
        const s16x8* pb = (const s16x8*)(WihP + (size_t)(n0 + row) * D_E + k0 + half * 16);
        *(s16x8*)&Bs[row][half * 16]     = pb[0];
        *(s16x8*)&Bs[row][half * 16 + 8] = pb[1];
        __syncthreads();
        int krow = (lane >> 4) * 8;
        f16x8 af[4], bfr[4];
#pragma unroll
        for (int i = 0; i < 4; ++i) af[i]  = *(const f16x8*)&As[wm + i * 16 + (lane & 15)][krow];
#pragma unroll
        for (int i = 0; i < 4; ++i) bfr[i] = *(const f16x8*)&Bs[wn + i * 16 + (lane & 15)][krow];
#pragma unroll
        for (int mi = 0; mi < 4; ++mi)
#pragma unroll
            for (int ni = 0; ni < 4; ++ni)
                acc[mi][ni] = __builtin_amdgcn_mfma_f32_16x16x32_f16(af[mi], bfr[ni], acc[mi][ni], 0, 0, 0);
        __syncthreads();
    }
#pragma unroll
    for (int mi = 0; mi < 4; ++mi) {
        int rbase = v0 + wm + mi * 16 + (lane >> 4) * 4;
#pragma unroll
        for (int ni = 0; ni < 4; ++ni) {
            int col = n0 + wn + ni * 16 + (lane & 15);
#pragma unroll
            for (int r = 0; r < 4; ++r) {
                int vr = rbase + r;
                if (vr < D_V) EG[(size_t)vr * D_G + col] = f2h(acc[mi][ni][r]);
            }
        }
    }
}

// ======================================================================
// lstm_seq: 256 WGs × 1 wave (rg 0..63 × bg 0..3). Round-7 structure plus:
//  - EG issued BEFORE poll (latency hides under flag wait; clean ladder)
//  - one atomic counter per bg (ctr >= 64*T), s_sleep backoff poll
//  - no per-step barriers (single wave; LDS ordering is program-order)
// ======================================================================
#define MFMA_HALF(Aar, MT, KH)                                                         \
    _Pragma("unroll")                                                                  \
    for (int ks = 0; ks < 8; ++ks) {                                                   \
        acc[MT][0] = __builtin_amdgcn_mfma_f32_16x16x32_f16(Aar[ks], bq[0][(KH)*8+ks], acc[MT][0], 0, 0, 0); \
        acc[MT][1] = __builtin_amdgcn_mfma_f32_16x16x32_f16(Aar[ks], bq[1][(KH)*8+ks], acc[MT][1], 0, 0, 0); \
    }

#define LSTM_PHASE(T, TOKC, TOKN)                                                      \
do {                                                                                   \
    int tnext = (T) + 1; if (tnext > D_T - 1) tnext = D_T - 1;                         \
    issue_tok(abT + (size_t)tnext * D_B + b, TOKN);                                    \
    f16x8 ec0, ec1, ec2, ec3;                                                          \
    issue_eg(EG + (size_t)(TOKC) * D_G + rg * 32, ec0, ec1, ec2, ec3);                 \
    if ((T) > 0) {                                                                     \
        const int tgt = 64 * (T);                                                      \
        int guard = 0;                                                                 \
        while (true) {                                                                 \
            int f = load_flag_llc(ctr);  /* vmcnt(0) inside: drains tok+eg too */      \
            if (f >= tgt) break;                                                       \
            if (++guard > (1 << 20)) break;                                            \
            __builtin_amdgcn_s_sleep(1);                                               \
        }                                                                              \
    } else {                                                                           \
        VWAIT(0);                                                                      \
    }                                                                                  \
    SBAR();                                                                            \
    const uint16_t* cur = hbuf + (size_t)((T) & 1) * (D_B * D_H);                      \
    const uint16_t* hb = cur + (size_t)bg * 4 * 8192 + lane * 8;                       \
    f16x8 A0[8], A1[8], A2[8], A3[8];                                                  \
    issue_h8(hb,                 A0);   /* m0 klo */                                   \
    issue_h8(hb + 4096,          A1);   /* m0 khi */                                   \
    issue_h8(hb + 8192,          A2);   /* m1 klo */                                   \
    issue_h8(hb + 12288,         A3);   /* m1 khi */                                   \
    f32x4 acc[4][2];                                                                   \
    _Pragma("unroll")                                                                  \
    for (int m = 0; m < 4; ++m) { acc[m][0] = (f32x4)0.0f; acc[m][1] = (f32x4)0.0f; }  \
    VWAIT(24); MFMA_HALF(A0, 0, 0); SBAR();                                            \
    issue_h8(hb + 16384, A0);           /* m2 klo */                                   \
    VWAIT(24); MFMA_HALF(A1, 0, 1); SBAR();                                            \
    issue_h8(hb + 20480, A1);           /* m2 khi */                                   \
    VWAIT(24); MFMA_HALF(A2, 1, 0); SBAR();                                            \
    issue_h8(hb + 24576, A2);           /* m3 klo */                                   \
    VWAIT(24); MFMA_HALF(A3, 1, 1); SBAR();                                            \
    issue_h8(hb + 28672, A3);           /* m3 khi */                                   \
    VWAIT(24); MFMA_HALF(A0, 2, 0); SBAR();                                            \
    VWAIT(16); MFMA_HALF(A1, 2, 1); SBAR();                                            \
    VWAIT(8);  MFMA_HALF(A2, 3, 0); SBAR();                                            \
    VWAIT(0);  MFMA_HALF(A3, 3, 1); SBAR();                                            \
    /* epilogue: acc -> gfull (single wave: LDS program-order, no barrier) */          \
    _Pragma("unroll")                                                                  \
    for (int mtt = 0; mtt < 4; ++mtt) {                                                \
        int br = mtt * 16 + (lane >> 4) * 4;                                           \
        _Pragma("unroll")                                                              \
        for (int nt2 = 0; nt2 < 2; ++nt2) {                                            \
            int n = nt2 * 16 + (lane & 15);                                            \
            _Pragma("unroll")                                                          \
            for (int r = 0; r < 4; ++r) gfull[br + r][n] = acc[mtt][nt2][r];           \
        }                                                                              \
    }                                                                                  \
    /* pointwise: g = gfull + bias + EG */                                             \
    float ev[32];                                                                      \
    _Pragma("unroll")                                                                  \
    for (int i = 0; i < 8; ++i) { ev[i] = (float)ec0[i]; ev[8 + i] = (float)ec1[i];    \
                                  ev[16 + i] = (float)ec2[i]; ev[24 + i] = (float)ec3[i]; } \
    f16x8 vh;                                                                          \
    _Pragma("unroll")                                                                  \
    for (int j = 0; j < 8; ++j) {                                                      \
        float gi = gfull[lane][j * 4 + 0] + bias_s[j * 4 + 0] + ev[j * 4 + 0];         \
        float gf = gfull[lane][j * 4 + 1] + bias_s[j * 4 + 1] + ev[j * 4 + 1];         \
        float gg = gfull[lane][j * 4 + 2] + bias_s[j * 4 + 2] + ev[j * 4 + 2];         \
        float go = gfull[lane][j * 4 + 3] + bias_s[j * 4 + 3] + ev[j * 4 + 3];         \
        float c2 = sigm(gf) * creg[j] + sigm(gi) * tanh_fast(gg);                      \
        float h2 = sigm(go) * tanh_fast(c2);                                           \
        creg[j] = c2;                                                                  \
        float rm = fmaxf(rreg[j], h2);                                                 \
        if (((T) & 31) == 31) {                                                        \
            reps[(size_t)((T) >> 5) * (D_B * D_H) + (size_t)b * D_H + rg * 8 + j] = rm;\
            rm = -1e30f;                                                               \
        }                                                                              \
        rreg[j] = rm;                                                                  \
        vh[j] = (_Float16)h2;                                                          \
    }                                                                                  \
    uint16_t* nxt = hbuf + (size_t)(((T) + 1) & 1) * (D_B * D_H);                      \
    store_h_nowait(nxt + (size_t)U * 8, vh);                                           \
    VWAIT(0);   /* drains reps stores + h store before publish */                      \
    if (lane == 0) atomicAdd(ctr, 1);   /* device-scope, fire-and-forget */            \
} while (0)

__global__ __launch_bounds__(64, 1) void lstm_seq_kernel(
    const int* __restrict__ abT, const uint16_t* __restrict__ EG,
    const uint16_t* __restrict__ WhhP, const float* __restrict__ biasP,
    uint16_t* __restrict__ hbuf, int* __restrict__ flags,
    float* __restrict__ reps)
{
    const int bid = blockIdx.x;
    const int rg = bid & 63;          // gate rowgroup 0..63
    const int bg = bid >> 6;          // batch group 0..3
    const int lane = threadIdx.x;     // 0..63
    __shared__ float gfull[64][33];
    __shared__ float bias_s[32];

    if (lane < 32) bias_s[lane] = biasP[rg * 32 + lane];

    float creg[8], rreg[8];
#pragma unroll
    for (int j = 0; j < 8; ++j) { creg[j] = 0.0f; rreg[j] = -1e30f; }

    // resident B fragments: Whh slice [32 rows][512 k] fp16 (cached loads)
    const uint16_t* Wp = WhhP + (size_t)rg * 32 * D_H;
    f16x8 bq[2][16];
#pragma unroll
    for (int nt = 0; nt < 2; ++nt)
#pragma unroll
        for (int ks = 0; ks < 16; ++ks)
            bq[nt][ks] = *(const f16x8*)(Wp + (size_t)(nt * 16 + (lane & 15)) * D_H + ks * 32 + ((lane >> 4) * 8));

    const int b = bg * 64 + lane;     // global batch row
    const int U = ((b >> 4) << 10) + ((rg >> 2) << 6) + ((rg & 3) << 4) + (b & 15);
    int* ctr = flags + bg * 32;       // one counter per bg (line-padded)

    int tok_a = abT[b];   // token for t=0 (compiler load, auto-waited)
    int tok_b;

    for (int t = 0; t < D_T; t += 2) {
        LSTM_PHASE(t,     tok_a, tok_b);
        LSTM_PHASE(t + 1, tok_b, tok_a);
    }
}

// ======================================================================
// predA (unchanged)
// ======================================================================
__global__ __launch_bounds__(256) void predA_kernel(
    const float* __restrict__ reps, const float* __restrict__ W1,
    const float* __restrict__ b1, float* __restrict__ A, float* __restrict__ A0)
{
    int gw = blockIdx.x * 4 + (threadIdx.x >> 6);
    int lane = threadIdx.x & 63;
    int s = gw >> 8, b = gw & 255;
    float accT[5] = {0, 0, 0, 0, 0};
    float acc0[5] = {0, 0, 0, 0, 0};
    for (int k = 0; k <= 2; ++k) {
        if (s - k < 0) break;
        const float* rp = reps + ((size_t)(s - k) * D_B + b) * D_H;
        const float* w  = W1 + (size_t)k * D_H * D_C;
        float part[5] = {0, 0, 0, 0, 0};
#pragma unroll
        for (int i = 0; i < 8; ++i) {
            int h = lane * 8 + i;
            float rv = rp[h];
#pragma unroll
            for (int c = 0; c < 5; ++c) part[c] += rv * w[h * 5 + c];
        }
#pragma unroll
        for (int c = 0; c < 5; ++c) { accT[c] += part[c]; if (k == 0) acc0[c] = part[c]; }
    }
#pragma unroll
    for (int m = 1; m < 64; m <<= 1)
#pragma unroll
        for (int c = 0; c < 5; ++c) {
            accT[c] += __shfl_xor(accT[c], m, 64);
            acc0[c] += __shfl_xor(acc0[c], m, 64);
        }
    if (lane == 0) {
#pragma unroll
        for (int c = 0; c < 5; ++c) A[((size_t)s * D_B + b) * D_C + c] = tanhf(accT[c] + b1[c]);
        if (s < 3)
#pragma unroll
            for (int c = 0; c < 5; ++c) A0[((size_t)s * D_B + b) * D_C + c] = tanhf(acc0[c] + b1[c]);
    }
}

// ======================================================================
// predOut (unchanged)
// ======================================================================
__global__ __launch_bounds__(256) void predOut_kernel(
    const float* __restrict__ A, const float* __restrict__ A0,
    const float* __restrict__ W2, const float* __restrict__ b2,
    float* __restrict__ out)
{
    int g = blockIdx.x * 256 + threadIdx.x;
    int b = g >> 4, s = g & 15;
    float v[5];
#pragma unroll
    for (int d = 0; d < 5; ++d) v[d] = b2[d];
    if (s < 3) {
        const float* Ar = A0 + ((size_t)s * D_B + b) * D_C;
#pragma unroll
        for (int c = 0; c < 5; ++c) {
            float a = Ar[c];
#pragma unroll
            for (int d = 0; d < 5; ++d) v[d] += a * W2[c * 5 + d];
        }
    } else {
        int i = s - 3;
        for (int tt = 0; tt < 4; ++tt) {
            const float* Ar = A + ((size_t)(tt + i) * D_B + b) * D_C;
            const float* w  = W2 + tt * 25;
#pragma unroll
            for (int c = 0; c < 5; ++c) {
                float a = Ar[c];
#pragma unroll
                for (int d = 0; d < 5; ++d) v[d] += a * w[c * 5 + d];
            }
        }
    }
    float m = v[0];
#pragma unroll
    for (int d = 1; d < 5; ++d) m = fmaxf(m, v[d]);
    float ssum = 0.0f;
#pragma unroll
    for (int d = 0; d < 5; ++d) ssum += expf(v[d] - m);
    float l = logf(ssum);
#pragma unroll
    for (int d = 0; d < 5; ++d) out[(size_t)b * 80 + d * 16 + s] = v[d] - m - l;
}

// ======================================================================
extern "C" void kernel_launch(void* const* d_in, const int* in_sizes, int n_in,
                              void* d_out, int out_size, void* d_ws, size_t ws_size,
                              hipStream_t stream)
{
    const int*   abstracts = (const int*)  d_in[0];
    const float* emb  = (const float*)d_in[1];
    const float* Wih  = (const float*)d_in[2];
    const float* Whh  = (const float*)d_in[3];
    const float* bih  = (const float*)d_in[4];
    const float* bhh  = (const float*)d_in[5];
    const float* W1   = (const float*)d_in[6];
    const float* b1   = (const float*)d_in[7];
    const float* W2   = (const float*)d_in[8];
    const float* b2   = (const float*)d_in[9];
    float* out = (float*)d_out;

    char* ws = (char*)d_ws;
    uint16_t* EG    = (uint16_t*)(ws + OFF_EG);
    uint16_t* embB  = (uint16_t*)(ws + OFF_EMB);
    uint16_t* WihP  = (uint16_t*)(ws + OFF_WIH);
    uint16_t* WhhP  = (uint16_t*)(ws + OFF_WHH);
    float*    biasP = (float*)   (ws + OFF_BIAS);
    uint16_t* hbuf  = (uint16_t*)(ws + OFF_HBUF);
    int*      flags = (int*)     (ws + OFF_FLAGS);
    float*    reps  = (float*)   (ws + OFF_REPS);
    float*    Abuf  = (float*)   (ws + OFF_A);
    float*    A0buf = (float*)   (ws + OFF_A0);
    int*      abT   = (int*)     (ws + OFF_ABT);

    prep_kernel<<<dim3(2048), dim3(256), 0, stream>>>(abstracts, emb, Wih, Whh, bih, bhh,
                                                      embB, WihP, WhhP, biasP, hbuf, flags, abT);
    egemm_kernel<<<dim3(16, 235), dim3(256), 0, stream>>>(embB, WihP, EG);
    lstm_seq_kernel<<<dim3(256), dim3(64), 0, stream>>>(abT, EG, WhhP, biasP,
                                                        hbuf, flags, reps);
    predA_kernel<<<dim3(1024), dim3(256), 0, stream>>>(reps, W1, b1, Abuf, A0buf);
    predOut_kernel<<<dim3(16), dim3(256), 0, stream>>>(Abuf, A0buf, W2, b2, out);
}